// Round 6
// baseline (298.788 us; speedup 1.0000x reference)
//
#include <hip/hip_runtime.h>

// 2-layer GCN: fused build mega-kernel (flag-pipelined) + bf16-MFMA gather.
//
// LESSON (R6-R8, measured): cooperative grid.sync costs ~250-300us EACH.
// This kernel instead uses device-scope atomic flag release/acquire between
// phases of ONE launch, with STRUCTURAL deadlock-safety: grid = 256 blocks
// <= 256 CUs, so all blocks are co-resident even at 1 block/CU worst case
// (1024 thr = 16 waves, 50KB LDS). Spinners back off with s_sleep.
// LESSON (R9): mean degree 16 -- hide gather latency via INDEPENDENT chains.
// LESSON (R13/R14): scatter fused into the ATOMIC pass regresses.
// LESSON (R15-R17, measured): k_gcn1 pinned ~46.5us by the random-gather
// path -- insensitive to occupancy, VALU work, index width. 79MB L2-miss
// side of 205MB logical, structural for 12.8MB working set vs 4MB/XCD L2.
// LESSON (R19, measured): random small accesses into >4MB tables thrash L2.
// LESSON (R20, measured): LDS-histogram rank beats 800K device atomics.
// LESSON (R21, measured): build kernels at 1 wave/SIMD are latency-bound.
// LESSON (R22, measured): u8 rank/coff + LDS-staged rows: -7us.
// LESSON (R23, measured): L2-resident exact CSR: neutral (-1us). Scatter
// drain was NOT a sink. Remaining budget is launch gaps + serialization
// (+ a 46us harness workspace-poison fill we cannot control).
// R24: fuse hist -> scan -> scatter||conversion into ONE kernel via flag
// pipeline; pack/pad ride along; finished hist/scan blocks join conversion.
// 5 dispatches -> 3 (memset16B, k_build, k_gcn1, k_gz).
//
//   memset : flags[2] = 0 (workspace arrives poisoned)
//   k_build: blocks [0,50)   LDS-histogram (u8 lrank/counts) -> flags[0]
//            blocks [50,99)  spin flags[0]==50 -> scan -> deg, rstart4,
//                            coff in-place offsets -> flags[1]
//            blocks [99,199) spin flags[1]==49 -> scatter csre (LDS-staged
//                            coff row) then join conversion
//            blocks [199,247) spin flags[1] -> xd = bf16(rsqrt(deg+1)*x)
//            blocks [247,255) W1 -> bf16 B-fragment pack ; block 255: pad
//            (hist/scan blocks join conversion after their release)
//   k_gcn1 : per 16-node tile: gather A[n]=dinv_n*(sum xd[s] + xd[n]) -> LDS,
//            zd = dinv * ( relu(A@W1 + b1) @ W2 ) via mfma_f32_16x16x32_bf16
//   k_gz   : out[i] = dinv[i]*(sum_{s in N(i)} zd[s] + zd[i]) + b2

#define N_NODES 50000
#define N_EDGES 800000
#define D_FEAT  128
#define D_HID   500
#define NTILES  3125              // 50000 / 16
#define BHIST   50                // histogram blocks
#define EPB     16000             // edges per histogram block (mult of 4)
#define NSCAN   49                // scan blocks (node groups of 1024)
#define SSPLIT  2                 // scatter blocks per histogram block
#define SBLK    (BHIST * SSPLIT)  // 100 scatter blocks
#define EPSB    (EPB / SSPLIT)    // 8000 edges per scatter block (mult of 4)
#define CONVB   48                // dedicated conversion blocks
#define NCONV   (SBLK + CONVB + BHIST + NSCAN)  // 247 conversion workers
#define PACK0   (BHIST + NSCAN + SBLK + CONVB)  // 247: first pack block
#define GSTRIDE 24576             // csre slots per 1024-node group
#define CSRE_SLOTS (NSCAN * GSTRIDE)            // 1,204,224 slots (2.41 MB)

typedef __bf16 bf16x8 __attribute__((ext_vector_type(8)));
typedef float  f32x4  __attribute__((ext_vector_type(4)));

static __device__ inline unsigned int f2bf(float f) {   // fp32 -> bf16, RTNE
    unsigned int u = __float_as_uint(f);
    return (u + 0x7fffu + ((u >> 16) & 1u)) >> 16;
}
static __device__ inline float bf_lo(unsigned int u) { return __uint_as_float(u << 16); }
static __device__ inline float bf_hi(unsigned int u) { return __uint_as_float(u & 0xffff0000u); }

static __device__ inline void add8(float* acc, uint4 u) {
    acc[0] += bf_lo(u.x);
    acc[1] += bf_hi(u.x);
    acc[2] += bf_lo(u.y);
    acc[3] += bf_hi(u.y);
    acc[4] += bf_lo(u.z);
    acc[5] += bf_hi(u.z);
    acc[6] += bf_lo(u.w);
    acc[7] += bf_hi(u.w);
}

static __device__ inline void spin_until(const int* f, int want) {
    // one spinner thread; agent-scope acquire load (bypasses stale L2)
    while (__hip_atomic_load(f, __ATOMIC_ACQUIRE, __HIP_MEMORY_SCOPE_AGENT) < want)
        __builtin_amdgcn_s_sleep(8);
}

// ---- k_build: whole build pipeline in one launch, 256 blocks x 1024 ----
__global__ __launch_bounds__(1024) void k_build(const int* __restrict__ src,
                                                const int* __restrict__ dst,
                                                const float* __restrict__ x,
                                                const float* __restrict__ W1,
                                                const float* __restrict__ b1,
                                                const float* __restrict__ W2,
                                                unsigned char* __restrict__ coff,
                                                unsigned char* __restrict__ lrank,
                                                unsigned int* __restrict__ rstart4,
                                                int* __restrict__ deg,
                                                unsigned short* __restrict__ csre,
                                                uint2* __restrict__ xd,
                                                unsigned short* __restrict__ b_pk,
                                                float* __restrict__ b1p,
                                                float* __restrict__ w2p,
                                                int* __restrict__ flags) {
    __shared__ unsigned int sbuf[N_NODES / 4];        // 50 KB, multi-use
    const int b = blockIdx.x, tid = threadIdx.x;
    int cid = -1;                                     // conversion worker id

    if (b < BHIST) {
        // ---- phase H: histogram + local rank (4 nodes per u32 word) ----
        for (int w = tid; w < N_NODES / 4; w += 1024) sbuf[w] = 0u;
        __syncthreads();
        const int base = b * EPB;
        for (int i = tid * 4; i < EPB; i += 4096) {   // 4 indep atomic chains
            int4 d4 = *(const int4*)&dst[base + i];
            unsigned int s0 = (unsigned int)(d4.x & 3) * 8u;
            unsigned int s1 = (unsigned int)(d4.y & 3) * 8u;
            unsigned int s2 = (unsigned int)(d4.z & 3) * 8u;
            unsigned int s3 = (unsigned int)(d4.w & 3) * 8u;
            unsigned int r0 = atomicAdd(&sbuf[d4.x >> 2], 1u << s0);
            unsigned int r1 = atomicAdd(&sbuf[d4.y >> 2], 1u << s1);
            unsigned int r2 = atomicAdd(&sbuf[d4.z >> 2], 1u << s2);
            unsigned int r3 = atomicAdd(&sbuf[d4.w >> 2], 1u << s3);
            uchar4 lr;
            lr.x = (unsigned char)((r0 >> s0) & 0xffu);
            lr.y = (unsigned char)((r1 >> s1) & 0xffu);
            lr.z = (unsigned char)((r2 >> s2) & 0xffu);
            lr.w = (unsigned char)((r3 >> s3) & 0xffu);
            *(uchar4*)&lrank[base + i] = lr;
        }
        __syncthreads();
        unsigned int* crow = (unsigned int*)coff + (size_t)b * (N_NODES / 4);
        for (int w = tid; w < N_NODES / 4; w += 1024) crow[w] = sbuf[w];
        __threadfence();                              // push to agent scope
        __syncthreads();
        if (tid == 0)
            __hip_atomic_fetch_add(&flags[0], 1, __ATOMIC_RELEASE,
                                   __HIP_MEMORY_SCOPE_AGENT);
        // join conversion below (needs flags[1])
        if (tid == 0) spin_until(&flags[1], NSCAN);
        __syncthreads();
        cid = SBLK + CONVB + b;                       // [148, 198)
    } else if (b < BHIST + NSCAN) {
        // ---- phase S: per-word prefix over 50 rows + group-local scan ----
        const int g = b - BHIST;
        if (tid == 0) spin_until(&flags[0], BHIST);
        __syncthreads();
        const int w = g * 256 + tid;                  // word index (4 nodes)
        const bool live = (tid < 256) && (w < N_NODES / 4);
        unsigned int run0 = 0, run1 = 0, run2 = 0, run3 = 0;
        if (live) {
            unsigned int* coffw = (unsigned int*)coff;
#pragma unroll 10
            for (int r = 0; r < BHIST; r++) {
                size_t i = (size_t)r * (N_NODES / 4) + w;
                unsigned int c = coffw[i];
                coffw[i] = run0 | (run1 << 8) | (run2 << 16) | (run3 << 24);
                run0 += c & 0xffu;
                run1 += (c >> 8) & 0xffu;
                run2 += (c >> 16) & 0xffu;
                run3 += (c >> 24) & 0xffu;
            }
            int4 d;
            d.x = (int)run0; d.y = (int)run1; d.z = (int)run2; d.w = (int)run3;
            *(int4*)&deg[w * 4] = d;
        }
        unsigned int s0 = (run0 + 3u) & ~3u, s1 = (run1 + 3u) & ~3u;
        unsigned int s2 = (run2 + 3u) & ~3u, s3 = (run3 + 3u) & ~3u;
        unsigned int tot = live ? (s0 + s1 + s2 + s3) : 0u;
        if (tid < 256) sbuf[tid] = tot;
        __syncthreads();
        for (int off = 1; off < 256; off <<= 1) {     // inclusive block scan
            unsigned int v = 0;
            if (tid < 256 && tid >= off) v = sbuf[tid - off];
            __syncthreads();
            if (tid < 256) sbuf[tid] += v;
            __syncthreads();
        }
        if (live) {
            unsigned int base = (unsigned int)g * GSTRIDE + (sbuf[tid] - tot);
            uint4 r;
            r.x = base;
            r.y = base + s0;
            r.z = base + s0 + s1;
            r.w = base + s0 + s1 + s2;
            *(uint4*)&rstart4[w * 4] = r;
        }
        __threadfence();
        __syncthreads();
        if (tid == 0)
            __hip_atomic_fetch_add(&flags[1], 1, __ATOMIC_RELEASE,
                                   __HIP_MEMORY_SCOPE_AGENT);
        cid = SBLK + CONVB + BHIST + g;               // [198, 247)
    } else if (b < BHIST + NSCAN + SBLK + CONVB) {
        // ---- phase F: scatter (first SBLK) / conversion-only (rest) ----
        if (tid == 0) spin_until(&flags[1], NSCAN);
        __syncthreads();
        if (b < BHIST + NSCAN + SBLK) {
            const int bs = b - BHIST - NSCAN;         // [0, 100)
            const int hb = bs >> 1;
            const unsigned int* crow =
                (const unsigned int*)coff + (size_t)hb * (N_NODES / 4);
            for (int w = tid; w < N_NODES / 4; w += 1024) sbuf[w] = crow[w];
            __syncthreads();
            const unsigned char* lcoff = (const unsigned char*)sbuf;
            const int base = hb * EPB + (bs & 1) * EPSB;
            for (int i = tid * 4; i < EPSB; i += 4096) {
                int4 s4 = *(const int4*)&src[base + i];
                int4 d4 = *(const int4*)&dst[base + i];
                uchar4 lr = *(const uchar4*)&lrank[base + i];
                unsigned int t0 = rstart4[d4.x] + (unsigned int)lcoff[d4.x] + lr.x;
                unsigned int t1 = rstart4[d4.y] + (unsigned int)lcoff[d4.y] + lr.y;
                unsigned int t2 = rstart4[d4.z] + (unsigned int)lcoff[d4.z] + lr.z;
                unsigned int t3 = rstart4[d4.w] + (unsigned int)lcoff[d4.w] + lr.w;
                if (t0 < CSRE_SLOTS) csre[t0] = (unsigned short)s4.x;
                if (t1 < CSRE_SLOTS) csre[t1] = (unsigned short)s4.y;
                if (t2 < CSRE_SLOTS) csre[t2] = (unsigned short)s4.z;
                if (t3 < CSRE_SLOTS) csre[t3] = (unsigned short)s4.w;
            }
            cid = bs;                                 // [0, 100)
        } else {
            cid = SBLK + (b - BHIST - NSCAN - SBLK);  // [100, 148)
        }
    } else if (b < PACK0 + 8) {                       // W1 -> B-fragment pack
        int idx  = (b - PACK0) * 1024 + tid;          // [0, 8192)
        int lane = idx & 63;
        int slot = idx >> 6;
        int t    = slot >> 2;                         // n-tile
        int ks   = slot & 3;                          // k-step
        int quad = lane >> 4;
        int n    = t * 16 + (lane & 15);
        unsigned int us[8];
#pragma unroll
        for (int j = 0; j < 8; j++) {
            int k = ks * 32 + quad * 8 + j;
            float v = (n < D_HID) ? W1[(size_t)k * D_HID + n] : 0.f;
            us[j] = f2bf(v);
        }
        uint4 p;
        p.x = us[0] | (us[1] << 16);
        p.y = us[2] | (us[3] << 16);
        p.z = us[4] | (us[5] << 16);
        p.w = us[6] | (us[7] << 16);
        ((uint4*)b_pk)[idx] = p;
        return;
    } else {                                          // pad b1 / W2 to 512
        if (tid < 512) {
            b1p[tid] = (tid < D_HID) ? b1[tid] : 0.f;
            w2p[tid] = (tid < D_HID) ? W2[tid] : 0.f;
        }
        return;
    }

    // ---- phase C: xd = bf16(rsqrt(deg+1)*x), 247 workers, coalesced ----
    for (int i = cid * 1024 + tid; i < N_NODES * D_FEAT / 4; i += NCONV * 1024) {
        float dv = rsqrtf((float)(deg[i >> 5] + 1));  // 32 float4 per node row
        float4 v = ((const float4*)x)[i];
        uint2 o;
        o.x = f2bf(dv * v.x) | (f2bf(dv * v.y) << 16);
        o.y = f2bf(dv * v.z) | (f2bf(dv * v.w) << 16);
        xd[i] = o;
    }
}

// Fused gather + bf16-MFMA MLP. Block = 16 nodes, 4 waves. Gather is
// QUARTER-WAVE-PER-NODE: 16 lanes own one node; lane p holds 16B of the row;
// 4-edge unroll -> 4 independent row loads in flight per quarter. Per-node
// base comes from rstart4 (4-slot aligned -> ushort4 loads stay 8B-aligned).
__global__ __launch_bounds__(256, 8) void k_gcn1(const uint4* __restrict__ xd4,
                                                 const unsigned short* __restrict__ csre,
                                                 const unsigned int* __restrict__ rstart4,
                                                 const int* __restrict__ deg,
                                                 const unsigned short* __restrict__ b_pk,
                                                 const float* __restrict__ b1p,
                                                 const float* __restrict__ w2p,
                                                 float* __restrict__ zd) {
    __shared__ unsigned short A[16][136];   // bf16 rows; 272B stride, 2-way alias = free
    __shared__ float red[4][16];
    const int t = threadIdx.x;
    const int node0 = blockIdx.x * 16;      // 50000 = 16 * 3125
    const int wv = t >> 6, lane = t & 63;
    const int q = lane >> 4, p = lane & 15;

    // ---- Phase 1: gather; quarter q of wave wv owns node n = wv*4+q ----
    {
        const int n = wv * 4 + q;
        const int node = node0 + n;
        int dg = deg[node];
        const unsigned int base = rstart4[node];
        uint4 su = xd4[(size_t)node * 16 + p];        // self-loop row, prefetched
        if (dg > 64) dg = 64;               // never fires; memory-safety guard
        float acc[8];
#pragma unroll
        for (int j = 0; j < 8; j++) acc[j] = 0.f;

        int e = 0;
        for (; e + 4 <= dg; e += 4) {       // 1 ushort4 index load + 4 rows in flight
            ushort4 s4 = *(const ushort4*)&csre[base + e];
            uint4 u0 = xd4[(size_t)s4.x * 16 + p];
            uint4 u1 = xd4[(size_t)s4.y * 16 + p];
            uint4 u2 = xd4[(size_t)s4.z * 16 + p];
            uint4 u3 = xd4[(size_t)s4.w * 16 + p];
            add8(acc, u0);
            add8(acc, u1);
            add8(acc, u2);
            add8(acc, u3);
        }
        for (; e < dg; e++) {
            int s = csre[base + e];
            uint4 u = xd4[(size_t)s * 16 + p];
            add8(acc, u);
        }

        // self-loop + finalize: A[n] = bf16( di * (acc + xd[node]) )
        const float di = rsqrtf((float)(dg + 1));
        uint4 o;
        o.x = f2bf(di * (acc[0] + bf_lo(su.x))) |
              (f2bf(di * (acc[1] + bf_hi(su.x))) << 16);
        o.y = f2bf(di * (acc[2] + bf_lo(su.y))) |
              (f2bf(di * (acc[3] + bf_hi(su.y))) << 16);
        o.z = f2bf(di * (acc[4] + bf_lo(su.z))) |
              (f2bf(di * (acc[5] + bf_hi(su.z))) << 16);
        o.w = f2bf(di * (acc[6] + bf_lo(su.w))) |
              (f2bf(di * (acc[7] + bf_hi(su.w))) << 16);
        *(uint4*)&A[n][p * 8] = o;
    }
    __syncthreads();

    // ---- Phase 2: D[16][512] via 16x16x32 bf16 MFMA; wave owns 8 n-tiles ----
    bf16x8 afr[4];
#pragma unroll
    for (int ks = 0; ks < 4; ks++)
        afr[ks] = *(const bf16x8*)&A[p][ks * 32 + q * 8];

    const bf16x8* __restrict__ bpk = (const bf16x8*)b_pk;
    f32x4 acc[8];
#pragma unroll
    for (int tt = 0; tt < 8; tt++) acc[tt] = (f32x4){0.f, 0.f, 0.f, 0.f};
#pragma unroll
    for (int tt = 0; tt < 8; tt++) {
        const int tile_n = wv * 8 + tt;
#pragma unroll
        for (int ks = 0; ks < 4; ks++) {
            bf16x8 bfr = bpk[(size_t)(tile_n * 4 + ks) * 64 + lane];
            acc[tt] = __builtin_amdgcn_mfma_f32_16x16x32_bf16(afr[ks], bfr, acc[tt], 0, 0, 0);
        }
    }

    // epilogue: zd-partial = relu(D + b1) . W2   (C/D: col=p, row=q*4+r)
    float zp[4] = {0.f, 0.f, 0.f, 0.f};
#pragma unroll
    for (int tt = 0; tt < 8; tt++) {
        const int c = (wv * 8 + tt) * 16 + p;
        const float b1v = b1p[c];
        const float w2v = w2p[c];
#pragma unroll
        for (int r = 0; r < 4; r++)
            zp[r] += fmaxf(acc[tt][r] + b1v, 0.f) * w2v;
    }
#pragma unroll
    for (int off = 1; off < 16; off <<= 1) {
#pragma unroll
        for (int r = 0; r < 4; r++) zp[r] += __shfl_xor(zp[r], off);
    }
    if (p == 0) {
#pragma unroll
        for (int r = 0; r < 4; r++) red[wv][q * 4 + r] = zp[r];
    }
    __syncthreads();
    if (t < 16) {
        int node = node0 + t;
        float zz = red[0][t] + red[1][t] + red[2][t] + red[3][t];
        zd[node] = rsqrtf((float)(deg[node] + 1)) * zz;
    }
}

// Layer-2 scalar gather: 16 lanes per node, shuffle-reduce (zd 200KB, L2-hot).
__global__ __launch_bounds__(256) void k_gz(const unsigned short* __restrict__ csre,
                                            const unsigned int* __restrict__ rstart4,
                                            const int* __restrict__ deg,
                                            const float* __restrict__ zd,
                                            const float* __restrict__ b2,
                                            float* __restrict__ out) {
    const int node = blockIdx.x * 16 + (threadIdx.x >> 4);
    const int l = threadIdx.x & 15;
    int dg = deg[node];
    if (dg > 64) dg = 64;
    const unsigned int base = rstart4[node];
    float s = 0.f;
    for (int e = l; e < dg; e += 16) s += zd[csre[base + e]];
#pragma unroll
    for (int off = 1; off < 16; off <<= 1) s += __shfl_xor(s, off);
    if (l == 0) {
        float di = rsqrtf((float)(dg + 1));
        out[node] = di * (s + zd[node]) + b2[0];
    }
}

extern "C" void kernel_launch(void* const* d_in, const int* in_sizes, int n_in,
                              void* d_out, int out_size, void* d_ws, size_t ws_size,
                              hipStream_t stream) {
    const float* x  = (const float*)d_in[0];
    const int*   ei = (const int*)d_in[1];     // [2, E]: row 0 = src, row 1 = dst
    const float* W1 = (const float*)d_in[2];
    const float* b1 = (const float*)d_in[3];
    const float* W2 = (const float*)d_in[4];
    const float* b2 = (const float*)d_in[5];
    float* out = (float*)d_out;

    const int* src = ei;
    const int* dst = ei + N_EDGES;

    // Workspace layout (~19.8 MB).
    uint2* xd            = (uint2*)d_ws;                       // 1,600,000 uint2 (12.8 MB)
    unsigned short* b_pk = (unsigned short*)(xd + 1600000);    // 65,536 bf16 (128 KB)
    float* b1p    = (float*)(b_pk + 65536);                    // 512
    float* w2p    = b1p + 512;                                 // 512
    float* zd     = w2p + 512;                                 // 50000 (200 KB)
    int* deg      = (int*)(zd + N_NODES);                      // 50000 (200 KB)
    unsigned int* rstart4 = (unsigned int*)(deg + N_NODES);    // 50000 u32 (200 KB)
    unsigned char* coff  = (unsigned char*)(rstart4 + N_NODES);// 50*50000 u8 (2.5 MB)
    unsigned char* lrank = coff + (size_t)BHIST * N_NODES;     // 800,000 u8
    unsigned short* csre = (unsigned short*)(lrank + N_EDGES); // 1,204,224 u16 (2.41 MB)
    int* flags    = (int*)(csre + CSRE_SLOTS);                 // 2 ints (+pad)

    hipMemsetAsync(flags, 0, 16, stream);              // workspace is poisoned

    k_build<<<256, 1024, 0, stream>>>(src, dst, x, W1, b1, W2, coff, lrank,
                                      rstart4, deg, csre, xd, b_pk, b1p, w2p,
                                      flags);
    k_gcn1<<<NTILES, 256, 0, stream>>>((const uint4*)xd, csre, rstart4, deg,
                                       b_pk, b1p, w2p, zd);
    k_gz  <<<NTILES, 256, 0, stream>>>(csre, rstart4, deg, zd, b2, out);
}

// Round 8
// 153.893 us; speedup vs baseline: 1.9415x; 1.9415x over previous
//
#include <hip/hip_runtime.h>

// 2-layer GCN, group-padded-exact-CSR gather + bf16-MFMA, 5 dispatches.
//
// LESSON (R6-R8, measured): cooperative grid.sync costs ~250-300us EACH.
// LESSON (R24, measured): hand-rolled flag-spin phase barriers inside one
// kernel are JUST AS BAD (k_build 198us, VALUBusy 1.1%) -- on MI355X any
// all-blocks-resident phase-barrier construct costs 100-250us. Phases must
// be separate dispatches; concurrency only WITHIN a dispatch.
// LESSON (R9): mean degree 16 -- hide gather latency via INDEPENDENT chains.
// LESSON (R13/R14): scatter fused into the atomic pass regresses.
// LESSON (R15-R17, measured): k_gcn1 pinned ~46.5us by the random-gather
// path -- insensitive to occupancy, VALU work, index width. Structural for
// a 12.8MB working set vs 4MB/XCD L2 on a random graph.
// LESSON (R19, measured): random small accesses into >4MB tables thrash L2.
// LESSON (R20, measured): LDS-histogram rank beats 800K device atomics.
// LESSON (R21, measured): build kernels at 1 wave/SIMD are latency-bound.
// LESSON (R22, measured): u8 rank/coff + LDS-staged rows: -7us.
// LESSON (R23, measured): L2-resident exact CSR: ~neutral. Budget now:
// poison-fill ~46us (harness, 268MB, timed, untouchable) + gcn1 46.4 +
// build smalls + gaps.
// R25 (resubmit; R7 bench was an infra failure, not a kernel verdict):
// free concurrency WITHOUT cross-block ordering: conversion only needs
// deg, and a conversion block can SELF-COMPUTE deg for its 252 nodes from
// the coff counts (63 words x 64 rows = 12.6KB sequential). So conversion
// rides in the SCAN dispatch (concurrent blocks, no ordering), and k_fill
// becomes scatter-only. Scan writes offsets to a separate boff buffer
// (conversion still reads counts -- no in-place overwrite race).
//
//   k_hist : 64 LDS-histogram blocks @1024thr (u8 lrank, u8 counts->coff)
//            | 8 W1-pack blocks | 1 pad block
//   k_scan2: blocks [0,49): per-word prefix over 64 rows (coff->boff) +
//            deg[n] + group-local scan -> absolute rstart4[n]
//            blocks [49,248): conversion; self-deg from coff slice in LDS,
//            xd = bf16(rsqrt(deg+1)*x) for its 252 nodes
//   k_fill : 320 scatter-only blocks; stage boff row in LDS;
//            csre[rstart4[dst]+boff[dst]+lrank[e]] = (u16)src
//   k_gcn1 : per 16-node tile: gather A[n]=dinv_n*(sum xd[s] + xd[n]) -> LDS,
//            zd = dinv * ( relu(A@W1 + b1) @ W2 ) via mfma_f32_16x16x32_bf16
//   k_gz   : out[i] = dinv[i]*(sum_{s in N(i)} zd[s] + zd[i]) + b2

#define N_NODES 50000
#define N_EDGES 800000
#define D_FEAT  128
#define D_HID   500
#define NTILES  3125              // 50000 / 16
#define BHIST   64                // histogram blocks
#define EPB     12500             // edges per histogram block (mult of 4)
#define NSCAN   49                // scan blocks (node groups of 1024)
#define NCONVB  199               // conversion blocks (252 nodes each)
#define NPBW    63                // coff words per conversion block
#define SSPLIT  5                 // scatter blocks per histogram block
#define SB      (BHIST * SSPLIT)  // 320 scatter blocks
#define EPSB    (EPB / SSPLIT)    // 2500 edges per scatter block (mult of 4)
#define GSTRIDE 24576             // csre slots per 1024-node group
#define CSRE_SLOTS (NSCAN * GSTRIDE)   // 1,204,224 slots (2.41 MB)

typedef __bf16 bf16x8 __attribute__((ext_vector_type(8)));
typedef float  f32x4  __attribute__((ext_vector_type(4)));

static __device__ inline unsigned int f2bf(float f) {   // fp32 -> bf16, RTNE
    unsigned int u = __float_as_uint(f);
    return (u + 0x7fffu + ((u >> 16) & 1u)) >> 16;
}
static __device__ inline float bf_lo(unsigned int u) { return __uint_as_float(u << 16); }
static __device__ inline float bf_hi(unsigned int u) { return __uint_as_float(u & 0xffff0000u); }

static __device__ inline void add8(float* acc, uint4 u) {
    acc[0] += bf_lo(u.x);
    acc[1] += bf_hi(u.x);
    acc[2] += bf_lo(u.y);
    acc[3] += bf_hi(u.y);
    acc[4] += bf_lo(u.z);
    acc[5] += bf_hi(u.z);
    acc[6] += bf_lo(u.w);
    acc[7] += bf_hi(u.w);
}

// ---- k_hist: [0,BHIST) LDS-histogram rank @1024thr | 8 W1-pack | 1 pad ----
// Histogram packs 4 nodes per u32 word (u8 counts, Poisson lambda=0.25/block).
__global__ __launch_bounds__(1024) void k_hist(const int* __restrict__ dst,
                                               const float* __restrict__ W1,
                                               const float* __restrict__ b1,
                                               const float* __restrict__ W2,
                                               unsigned char* __restrict__ coff,
                                               unsigned char* __restrict__ lrank,
                                               unsigned short* __restrict__ b_pk,
                                               float* __restrict__ b1p,
                                               float* __restrict__ w2p) {
    __shared__ unsigned int hist[N_NODES / 4];        // 12500 words = 50 KB
    const int b = blockIdx.x, tid = threadIdx.x;
    if (b < BHIST) {                                  // histogram + local rank
        for (int w = tid; w < N_NODES / 4; w += 1024) hist[w] = 0u;
        __syncthreads();
        const int base = b * EPB;
        for (int i = tid * 4; i < EPB; i += 4096) {   // 4 indep atomic chains
            int4 d4 = *(const int4*)&dst[base + i];
            unsigned int s0 = (unsigned int)(d4.x & 3) * 8u;
            unsigned int s1 = (unsigned int)(d4.y & 3) * 8u;
            unsigned int s2 = (unsigned int)(d4.z & 3) * 8u;
            unsigned int s3 = (unsigned int)(d4.w & 3) * 8u;
            unsigned int r0 = atomicAdd(&hist[d4.x >> 2], 1u << s0);
            unsigned int r1 = atomicAdd(&hist[d4.y >> 2], 1u << s1);
            unsigned int r2 = atomicAdd(&hist[d4.z >> 2], 1u << s2);
            unsigned int r3 = atomicAdd(&hist[d4.w >> 2], 1u << s3);
            uchar4 lr;
            lr.x = (unsigned char)((r0 >> s0) & 0xffu);
            lr.y = (unsigned char)((r1 >> s1) & 0xffu);
            lr.z = (unsigned char)((r2 >> s2) & 0xffu);
            lr.w = (unsigned char)((r3 >> s3) & 0xffu);
            *(uchar4*)&lrank[base + i] = lr;
        }
        __syncthreads();
        unsigned int* crow = (unsigned int*)coff + (size_t)b * (N_NODES / 4);
        for (int w = tid; w < N_NODES / 4; w += 1024) crow[w] = hist[w];
    } else if (b < BHIST + 8) {                       // W1 -> B-fragment pack
        int idx  = (b - BHIST) * 1024 + tid;          // [0, 8192)
        int lane = idx & 63;
        int slot = idx >> 6;
        int t    = slot >> 2;                         // n-tile
        int ks   = slot & 3;                          // k-step
        int quad = lane >> 4;
        int n    = t * 16 + (lane & 15);
        unsigned int us[8];
#pragma unroll
        for (int j = 0; j < 8; j++) {
            int k = ks * 32 + quad * 8 + j;
            float v = (n < D_HID) ? W1[(size_t)k * D_HID + n] : 0.f;
            us[j] = f2bf(v);
        }
        uint4 p;
        p.x = us[0] | (us[1] << 16);
        p.y = us[2] | (us[3] << 16);
        p.z = us[4] | (us[5] << 16);
        p.w = us[6] | (us[7] << 16);
        ((uint4*)b_pk)[idx] = p;
    } else {                                          // pad b1 / W2 to 512
        if (tid < 512) {
            b1p[tid] = (tid < D_HID) ? b1[tid] : 0.f;
            w2p[tid] = (tid < D_HID) ? W2[tid] : 0.f;
        }
    }
}

// ---- k_scan2: scan blocks [0,49) || conversion blocks [49,248) ----
// Scan: per-word prefix over 64 count rows (coff -> boff, counts PRESERVED),
// deg totals, group-local 4-aligned scan -> absolute rstart4.
// Conversion: self-compute deg for its 252 nodes from coff (63 words x 64
// rows, LDS-accumulated), then xd = bf16(rsqrt(deg+1)*x). No ordering deps.
__global__ __launch_bounds__(1024) void k_scan2(const unsigned int* __restrict__ coffw,
                                                unsigned int* __restrict__ boffw,
                                                int* __restrict__ deg,
                                                unsigned int* __restrict__ rstart4,
                                                const float* __restrict__ x,
                                                uint2* __restrict__ xd) {
    const int b = blockIdx.x, tid = threadIdx.x;
    if (b < NSCAN) {
        __shared__ unsigned int ps[256];
        const int w = b * 256 + tid;                  // word index (4 nodes)
        const bool live = (tid < 256) && (w < N_NODES / 4);
        unsigned int run0 = 0, run1 = 0, run2 = 0, run3 = 0;
        if (live) {
#pragma unroll 8
            for (int r = 0; r < BHIST; r++) {
                size_t i = (size_t)r * (N_NODES / 4) + w;
                unsigned int c = coffw[i];
                boffw[i] = run0 | (run1 << 8) | (run2 << 16) | (run3 << 24);
                run0 += c & 0xffu;
                run1 += (c >> 8) & 0xffu;
                run2 += (c >> 16) & 0xffu;
                run3 += (c >> 24) & 0xffu;
            }
            int4 d;
            d.x = (int)run0; d.y = (int)run1; d.z = (int)run2; d.w = (int)run3;
            *(int4*)&deg[w * 4] = d;
        }
        unsigned int s0 = (run0 + 3u) & ~3u, s1 = (run1 + 3u) & ~3u;
        unsigned int s2 = (run2 + 3u) & ~3u, s3 = (run3 + 3u) & ~3u;
        unsigned int tot = live ? (s0 + s1 + s2 + s3) : 0u;
        if (tid < 256) ps[tid] = tot;
        __syncthreads();
        for (int off = 1; off < 256; off <<= 1) {     // inclusive block scan
            unsigned int v = 0;
            if (tid < 256 && tid >= off) v = ps[tid - off];
            __syncthreads();
            if (tid < 256) ps[tid] += v;
            __syncthreads();
        }
        if (live) {
            unsigned int base = (unsigned int)b * GSTRIDE + (ps[tid] - tot);
            uint4 r;
            r.x = base;
            r.y = base + s0;
            r.z = base + s0 + s1;
            r.w = base + s0 + s1 + s2;
            *(uint4*)&rstart4[w * 4] = r;
        }
    } else {                                          // conversion worker
        __shared__ unsigned int ldw[NPBW];            // packed u8 deg, 252 nodes
        const int cb = b - NSCAN;                     // [0, NCONVB)
        if (tid < NPBW) ldw[tid] = 0u;
        __syncthreads();
        for (int k = tid; k < BHIST * NPBW; k += 1024) {   // 4032 pairs
            int r  = k / NPBW;
            int wl = k - r * NPBW;
            int w  = cb * NPBW + wl;
            if (w < N_NODES / 4)
                atomicAdd(&ldw[wl], coffw[(size_t)r * (N_NODES / 4) + w]);
        }
        __syncthreads();
        for (int j = tid; j < 252 * 32; j += 1024) {  // 252 nodes x 32 float4
            int i = cb * 8064 + j;
            if (i < N_NODES * D_FEAT / 4) {
                int nl = j >> 5;
                unsigned int dgb = (ldw[nl >> 2] >> ((nl & 3) * 8)) & 0xffu;
                float dv = rsqrtf((float)(dgb + 1u));
                float4 v = ((const float4*)x)[i];
                uint2 o;
                o.x = f2bf(dv * v.x) | (f2bf(dv * v.y) << 16);
                o.y = f2bf(dv * v.z) | (f2bf(dv * v.w) << 16);
                xd[i] = o;
            }
        }
    }
}

// Scatter-only into the 2.4MB L2-resident exact CSR: block b serves hist row
// b/SSPLIT (boff offset row staged in LDS), 2500 edges, 4/thread, 1 iter.
__global__ __launch_bounds__(1024) void k_fill(const int* __restrict__ src,
                                               const int* __restrict__ dst,
                                               const unsigned char* __restrict__ boff,
                                               const unsigned char* __restrict__ lrank,
                                               const unsigned int* __restrict__ rstart4,
                                               unsigned short* __restrict__ csre) {
    __shared__ unsigned int sbuf[N_NODES / 4];        // 50 KB offset row
    const int b = blockIdx.x, tid = threadIdx.x;
    const int hb = b / SSPLIT;
    const unsigned int* brow =
        (const unsigned int*)boff + (size_t)hb * (N_NODES / 4);
    for (int w = tid; w < N_NODES / 4; w += 1024) sbuf[w] = brow[w];
    __syncthreads();
    const unsigned char* lcoff = (const unsigned char*)sbuf;
    const int base = b * EPSB;                        // mult of 4 (2500)
    for (int i = tid * 4; i < EPSB; i += 4096) {      // 1 iter, tid < 625
        int4 s4 = *(const int4*)&src[base + i];
        int4 d4 = *(const int4*)&dst[base + i];
        uchar4 lr = *(const uchar4*)&lrank[base + i];
        unsigned int t0 = rstart4[d4.x] + (unsigned int)lcoff[d4.x] + lr.x;
        unsigned int t1 = rstart4[d4.y] + (unsigned int)lcoff[d4.y] + lr.y;
        unsigned int t2 = rstart4[d4.z] + (unsigned int)lcoff[d4.z] + lr.z;
        unsigned int t3 = rstart4[d4.w] + (unsigned int)lcoff[d4.w] + lr.w;
        if (t0 < CSRE_SLOTS) csre[t0] = (unsigned short)s4.x;
        if (t1 < CSRE_SLOTS) csre[t1] = (unsigned short)s4.y;
        if (t2 < CSRE_SLOTS) csre[t2] = (unsigned short)s4.z;
        if (t3 < CSRE_SLOTS) csre[t3] = (unsigned short)s4.w;
    }
}

// Fused gather + bf16-MFMA MLP. Block = 16 nodes, 4 waves. Gather is
// QUARTER-WAVE-PER-NODE: 16 lanes own one node; lane p holds 16B of the row;
// 4-edge unroll -> 4 independent row loads in flight per quarter. Per-node
// base comes from rstart4 (4-slot aligned -> ushort4 loads stay 8B-aligned).
__global__ __launch_bounds__(256, 8) void k_gcn1(const uint4* __restrict__ xd4,
                                                 const unsigned short* __restrict__ csre,
                                                 const unsigned int* __restrict__ rstart4,
                                                 const int* __restrict__ deg,
                                                 const unsigned short* __restrict__ b_pk,
                                                 const float* __restrict__ b1p,
                                                 const float* __restrict__ w2p,
                                                 float* __restrict__ zd) {
    __shared__ unsigned short A[16][136];   // bf16 rows; 272B stride, 2-way alias = free
    __shared__ float red[4][16];
    const int t = threadIdx.x;
    const int node0 = blockIdx.x * 16;      // 50000 = 16 * 3125
    const int wv = t >> 6, lane = t & 63;
    const int q = lane >> 4, p = lane & 15;

    // ---- Phase 1: gather; quarter q of wave wv owns node n = wv*4+q ----
    {
        const int n = wv * 4 + q;
        const int node = node0 + n;
        int dg = deg[node];
        const unsigned int base = rstart4[node];
        uint4 su = xd4[(size_t)node * 16 + p];        // self-loop row, prefetched
        if (dg > 64) dg = 64;               // never fires; memory-safety guard
        float acc[8];
#pragma unroll
        for (int j = 0; j < 8; j++) acc[j] = 0.f;

        int e = 0;
        for (; e + 4 <= dg; e += 4) {       // 1 ushort4 index load + 4 rows in flight
            ushort4 s4 = *(const ushort4*)&csre[base + e];
            uint4 u0 = xd4[(size_t)s4.x * 16 + p];
            uint4 u1 = xd4[(size_t)s4.y * 16 + p];
            uint4 u2 = xd4[(size_t)s4.z * 16 + p];
            uint4 u3 = xd4[(size_t)s4.w * 16 + p];
            add8(acc, u0);
            add8(acc, u1);
            add8(acc, u2);
            add8(acc, u3);
        }
        for (; e < dg; e++) {
            int s = csre[base + e];
            uint4 u = xd4[(size_t)s * 16 + p];
            add8(acc, u);
        }

        // self-loop + finalize: A[n] = bf16( di * (acc + xd[node]) )
        const float di = rsqrtf((float)(dg + 1));
        uint4 o;
        o.x = f2bf(di * (acc[0] + bf_lo(su.x))) |
              (f2bf(di * (acc[1] + bf_hi(su.x))) << 16);
        o.y = f2bf(di * (acc[2] + bf_lo(su.y))) |
              (f2bf(di * (acc[3] + bf_hi(su.y))) << 16);
        o.z = f2bf(di * (acc[4] + bf_lo(su.z))) |
              (f2bf(di * (acc[5] + bf_hi(su.z))) << 16);
        o.w = f2bf(di * (acc[6] + bf_lo(su.w))) |
              (f2bf(di * (acc[7] + bf_hi(su.w))) << 16);
        *(uint4*)&A[n][p * 8] = o;
    }
    __syncthreads();

    // ---- Phase 2: D[16][512] via 16x16x32 bf16 MFMA; wave owns 8 n-tiles ----
    bf16x8 afr[4];
#pragma unroll
    for (int ks = 0; ks < 4; ks++)
        afr[ks] = *(const bf16x8*)&A[p][ks * 32 + q * 8];

    const bf16x8* __restrict__ bpk = (const bf16x8*)b_pk;
    f32x4 acc[8];
#pragma unroll
    for (int tt = 0; tt < 8; tt++) acc[tt] = (f32x4){0.f, 0.f, 0.f, 0.f};
#pragma unroll
    for (int tt = 0; tt < 8; tt++) {
        const int tile_n = wv * 8 + tt;
#pragma unroll
        for (int ks = 0; ks < 4; ks++) {
            bf16x8 bfr = bpk[(size_t)(tile_n * 4 + ks) * 64 + lane];
            acc[tt] = __builtin_amdgcn_mfma_f32_16x16x32_bf16(afr[ks], bfr, acc[tt], 0, 0, 0);
        }
    }

    // epilogue: zd-partial = relu(D + b1) . W2   (C/D: col=p, row=q*4+r)
    float zp[4] = {0.f, 0.f, 0.f, 0.f};
#pragma unroll
    for (int tt = 0; tt < 8; tt++) {
        const int c = (wv * 8 + tt) * 16 + p;
        const float b1v = b1p[c];
        const float w2v = w2p[c];
#pragma unroll
        for (int r = 0; r < 4; r++)
            zp[r] += fmaxf(acc[tt][r] + b1v, 0.f) * w2v;
    }
#pragma unroll
    for (int off = 1; off < 16; off <<= 1) {
#pragma unroll
        for (int r = 0; r < 4; r++) zp[r] += __shfl_xor(zp[r], off);
    }
    if (p == 0) {
#pragma unroll
        for (int r = 0; r < 4; r++) red[wv][q * 4 + r] = zp[r];
    }
    __syncthreads();
    if (t < 16) {
        int node = node0 + t;
        float zz = red[0][t] + red[1][t] + red[2][t] + red[3][t];
        zd[node] = rsqrtf((float)(deg[node] + 1)) * zz;
    }
}

// Layer-2 scalar gather: 16 lanes per node, shuffle-reduce (zd 200KB, L2-hot).
__global__ __launch_bounds__(256) void k_gz(const unsigned short* __restrict__ csre,
                                            const unsigned int* __restrict__ rstart4,
                                            const int* __restrict__ deg,
                                            const float* __restrict__ zd,
                                            const float* __restrict__ b2,
                                            float* __restrict__ out) {
    const int node = blockIdx.x * 16 + (threadIdx.x >> 4);
    const int l = threadIdx.x & 15;
    int dg = deg[node];
    if (dg > 64) dg = 64;
    const unsigned int base = rstart4[node];
    float s = 0.f;
    for (int e = l; e < dg; e += 16) s += zd[csre[base + e]];
#pragma unroll
    for (int off = 1; off < 16; off <<= 1) s += __shfl_xor(s, off);
    if (l == 0) {
        float di = rsqrtf((float)(dg + 1));
        out[node] = di * (s + zd[node]) + b2[0];
    }
}

extern "C" void kernel_launch(void* const* d_in, const int* in_sizes, int n_in,
                              void* d_out, int out_size, void* d_ws, size_t ws_size,
                              hipStream_t stream) {
    const float* x  = (const float*)d_in[0];
    const int*   ei = (const int*)d_in[1];     // [2, E]: row 0 = src, row 1 = dst
    const float* W1 = (const float*)d_in[2];
    const float* b1 = (const float*)d_in[3];
    const float* W2 = (const float*)d_in[4];
    const float* b2 = (const float*)d_in[5];
    float* out = (float*)d_out;

    const int* src = ei;
    const int* dst = ei + N_EDGES;

    // Workspace layout (~23.7 MB).
    uint2* xd            = (uint2*)d_ws;                       // 1,600,000 uint2 (12.8 MB)
    unsigned short* b_pk = (unsigned short*)(xd + 1600000);    // 65,536 bf16 (128 KB)
    float* b1p    = (float*)(b_pk + 65536);                    // 512
    float* w2p    = b1p + 512;                                 // 512
    float* zd     = w2p + 512;                                 // 50000 (200 KB)
    int* deg      = (int*)(zd + N_NODES);                      // 50000 (200 KB)
    unsigned int* rstart4 = (unsigned int*)(deg + N_NODES);    // 50000 u32 (200 KB)
    unsigned char* coff  = (unsigned char*)(rstart4 + N_NODES);// 64*50000 u8 (3.2 MB)
    unsigned char* boff  = coff + (size_t)BHIST * N_NODES;     // 64*50000 u8 (3.2 MB)
    unsigned char* lrank = boff + (size_t)BHIST * N_NODES;     // 800,000 u8
    unsigned short* csre = (unsigned short*)(lrank + N_EDGES); // 1,204,224 u16 (2.41 MB)

    k_hist<<<BHIST + 9, 1024, 0, stream>>>(dst, W1, b1, W2, coff, lrank,
                                           b_pk, b1p, w2p);
    k_scan2<<<NSCAN + NCONVB, 1024, 0, stream>>>((unsigned int*)coff,
                                                 (unsigned int*)boff, deg,
                                                 rstart4, x, xd);
    k_fill<<<SB, 1024, 0, stream>>>(src, dst, boff, lrank, rstart4, csre);
    k_gcn1<<<NTILES, 256, 0, stream>>>((const uint4*)xd, csre, rstart4, deg,
                                       b_pk, b1p, w2p, zd);
    k_gz  <<<NTILES, 256, 0, stream>>>(csre, rstart4, deg, zd, b2, out);
}